// Round 10
// baseline (7457.105 us; speedup 1.0000x reference)
//
#include <hip/hip_runtime.h>
#include <math.h>
#include <stdint.h>

#define B 128
#define S 512
#define V 6000
#define E 100
#define H 256
#define G4 1024   /* 4*H */
#define T 9

/* W per-gate float4 k-group split (64 groups of 4 cols per gate row) */
#define NVG 9              /* k-groups [0,9)   in arch VGPRs: 9*4*4 = 144 regs */
#define NAG 16             /* k-groups [9,25)  in AGPRs: 16*4*4 = 256 AGPRs */
#define NLD 3              /* k-groups [25,28) in LDS: 48 KB */
#define NST 36             /* k-groups [28,64) streamed: 576 KB/step/dir */
#define GST (NVG + NAG + NLD)   /* 28: first streamed k-group */

/* workspace byte offsets (256-aligned) */
#define OFF_PEMB_F 0u
#define PEMB_BYTES (V*G4*4u)                    /* 24,576,000 */
#define OFF_PEMB_B (OFF_PEMB_F + PEMB_BYTES)
#define OFF_EMF    (OFF_PEMB_B + PEMB_BYTES)    /* 49,152,000 */
#define EM_BYTES   (B*S*T*4u)                   /* 2,359,296 */
#define OFF_EMB    (OFF_EMF + EM_BYTES)
#define OFF_BP     (OFF_EMB + EM_BYTES)         /* 53,870,592 */
#define BP_BYTES   ((S-1)*B*16u)                /* 1,046,528 */
#define OFF_LT     (OFF_BP + BP_BYTES)
#define OFF_PT     (OFF_LT + 512u)
/* Streamed-W: 2 dirs x 4 gates x 36 groups x 256 lanes x 16 B = 1,179,648 B.
   OVERLAYS BP/LT/PT (1,309,184 B): k_prep writes + k_lstm reads strictly
   BEFORE k_vit/k_back write BP/LT/PT (stream-ordered). */
#define OFF_WSTREAM OFF_BP

__device__ __forceinline__ float sigf(float x) { return 1.0f / (1.0f + expf(-x)); }

/* pemb[v][g4] = bias[g4] + sum_e emb[v][e] * W_ih[g4][e],  g4 = q*H + j */
__global__ __launch_bounds__(256) void k_pemb(const float* __restrict__ emb,
                                              const float* __restrict__ wf, const float* __restrict__ bf,
                                              const float* __restrict__ wb, const float* __restrict__ bb,
                                              char* __restrict__ ws) {
    int blk = blockIdx.x;                   /* 0..749 */
    int d   = blk >= 375;
    int vb  = d ? blk - 375 : blk;
    const float* W    = d ? wb : wf;
    const float* bias = d ? bb : bf;
    float* pe = (float*)(ws + (d ? OFF_PEMB_B : OFF_PEMB_F));

    __shared__ float es[16 * E];
    for (int i = threadIdx.x; i < 16 * E; i += 256) es[i] = emb[vb * 16 * E + i];
    __syncthreads();

    int j = threadIdx.x;
    float acc[4][16];
    #pragma unroll
    for (int q = 0; q < 4; q++) {
        float bq = bias[q * H + j];
        #pragma unroll
        for (int v = 0; v < 16; v++) acc[q][v] = bq;
    }
    for (int e = 0; e < E; e++) {
        float w0 = W[(0 * H + j) * E + e];
        float w1 = W[(1 * H + j) * E + e];
        float w2 = W[(2 * H + j) * E + e];
        float w3 = W[(3 * H + j) * E + e];
        #pragma unroll
        for (int v = 0; v < 16; v++) {
            float x = es[v * E + e];
            acc[0][v] += w0 * x; acc[1][v] += w1 * x;
            acc[2][v] += w2 * x; acc[3][v] += w3 * x;
        }
    }
    for (int v = 0; v < 16; v++)
        #pragma unroll
        for (int q = 0; q < 4; q++)
            pe[(vb * 16 + v) * G4 + q * H + j] = acc[q][v];
}

/* streamed-W layout: wstr[((d*4+q)*NST + gi)*256 + j] = float4 W_d[q*256+j][4*(GST+gi)..+3]
   -> per step, lane j loads consecutive float4 (coalesced 16 B/lane) */
__global__ __launch_bounds__(256) void k_prep(const float* __restrict__ whhf,
                                              const float* __restrict__ whhb,
                                              char* __restrict__ ws) {
    int tid = blockIdx.x * 256 + threadIdx.x;   /* 2*4*36*256 = 73728 */
    if (tid >= 2 * 4 * NST * 256) return;
    int d   = tid >= 4 * NST * 256;
    int idx = d ? tid - 4 * NST * 256 : tid;
    int q  = idx / (NST * 256);
    int r2 = idx % (NST * 256);
    int gi = r2 >> 8, j = r2 & 255;
    const float* whh = d ? whhb : whhf;
    float4* wstr = (float4*)(ws + OFF_WSTREAM);
    const float4* src = (const float4*)(whh + (size_t)(q * H + j) * H);
    wstr[((size_t)((d * 4 + q) * NST + gi) << 8) + j] = src[GST + gi];
}

/* Single-CU LSTM, thread = hidden unit. 256 blocks (dir = blk>>7, b = blk&127)
   x 256 threads (4 waves = 1 wave/SIMD; AGPR usage forces this occupancy).
   Thread t owns unit j=t: all 4 gate rows (t, 256+t, 512+t, 768+t) ->
   activation is thread-local (no gate exchange; 2 barriers/step).
   W per thread (1024 floats): k-groups [0,9) arch VGPR (144, pinned),
   [9,25) AGPR (256, via v_accvgpr_write/read inline asm -- the file the
   R7-R9 allocator fights cannot touch), [25,28) LDS (48 KB),
   [28,64) streamed from L2 (576 KB/step, k-major, dir-shared). */
__global__ __launch_bounds__(256, 1) void k_lstm(const int* __restrict__ data,
                                                 const float* __restrict__ whhf,
                                                 const float* __restrict__ whhb,
                                                 const float* __restrict__ mlpW,
                                                 char* __restrict__ ws) {
    int blk = blockIdx.x;
    int d = blk >> 7, b = blk & 127;
    const float* whh = d ? whhb : whhf;
    const float* pe  = (const float*)(ws + (d ? OFF_PEMB_B : OFF_PEMB_F));
    float* emdst = (float*)(ws + (d ? OFF_EMB : OFF_EMF));
    const float4* wstr = (const float4*)(ws + OFF_WSTREAM);

    __shared__ __align__(16) float hs[H];      /* h_prev, 1 KB */
    __shared__ float4 sW[NLD * 4 * 256];       /* 48 KB: [(g*4+q)<<8 | t] */
    __shared__ float  red[T][4];
    __shared__ int    toks[S];                 /* 2 KB */

    int t = threadIdx.x;                       /* unit j */

    /* --- arch-VGPR W: k-groups [0,NVG) x 4 gates --- */
    float4 wv[NVG * 4];
    #pragma unroll
    for (int g = 0; g < NVG; g++)
        #pragma unroll
        for (int q = 0; q < 4; q++)
            wv[g * 4 + q] = ((const float4*)(whh + (size_t)(q * H + t) * H))[g];
    #pragma unroll
    for (int i = 0; i < NVG * 4; i++)
        asm volatile("" : "+v"(wv[i].x), "+v"(wv[i].y), "+v"(wv[i].z), "+v"(wv[i].w));

    /* --- AGPR W: k-groups [NVG, NVG+NAG) x 4 gates = 256 AGPRs --- */
    float ag[NAG * 4 * 4];
    #pragma unroll
    for (int g = 0; g < NAG; g++)
        #pragma unroll
        for (int q = 0; q < 4; q++) {
            float4 w = ((const float4*)(whh + (size_t)(q * H + t) * H))[NVG + g];
            int base = (g * 4 + q) * 4;
            asm volatile("v_accvgpr_write_b32 %0, %1" : "=a"(ag[base + 0]) : "v"(w.x));
            asm volatile("v_accvgpr_write_b32 %0, %1" : "=a"(ag[base + 1]) : "v"(w.y));
            asm volatile("v_accvgpr_write_b32 %0, %1" : "=a"(ag[base + 2]) : "v"(w.z));
            asm volatile("v_accvgpr_write_b32 %0, %1" : "=a"(ag[base + 3]) : "v"(w.w));
        }

    /* --- LDS W slab: k-groups [NVG+NAG, GST) --- */
    #pragma unroll
    for (int g = 0; g < NLD; g++)
        #pragma unroll
        for (int q = 0; q < 4; q++)
            sW[((g * 4 + q) << 8) + t] = ((const float4*)(whh + (size_t)(q * H + t) * H))[NVG + NAG + g];

    toks[t] = data[b * S + t];
    toks[t + 256] = data[b * S + t + 256];

    float mw[T];
    #pragma unroll
    for (int tt = 0; tt < T; tt++) mw[tt] = mlpW[tt * (2 * H) + d * H + t];

    hs[t] = 0.0f;
    float cst = 0.0f;
    __syncthreads();

    const float4* hs4 = (const float4*)hs;
    const float4* ws0 = wstr + (((size_t)(d * 4 + 0) * NST) << 8) + t;
    const float4* ws1 = wstr + (((size_t)(d * 4 + 1) * NST) << 8) + t;
    const float4* ws2 = wstr + (((size_t)(d * 4 + 2) * NST) << 8) + t;
    const float4* ws3 = wstr + (((size_t)(d * 4 + 3) * NST) << 8) + t;

    float pf0, pf1, pf2, pf3;
    {
        int sp0 = d ? (S - 1) : 0;
        size_t tok = (size_t)toks[sp0];
        pf0 = pe[(tok << 10) + 0 * H + t];
        pf1 = pe[(tok << 10) + 1 * H + t];
        pf2 = pe[(tok << 10) + 2 * H + t];
        pf3 = pe[(tok << 10) + 3 * H + t];
    }

    for (int ss = 0; ss < S; ss++) {
        int sp = d ? (S - 1 - ss) : ss;
        float a0 = pf0, a1 = pf1, a2 = pf2, a3 = pf3;
        if (ss + 1 < S) {
            int spn = d ? (S - 2 - ss) : (ss + 1);
            size_t tok = (size_t)toks[spn];
            pf0 = pe[(tok << 10) + 0 * H + t];
            pf1 = pe[(tok << 10) + 1 * H + t];
            pf2 = pe[(tok << 10) + 2 * H + t];
            pf3 = pe[(tok << 10) + 3 * H + t];
        }

        /* arch-VGPR phase */
        #pragma unroll
        for (int g = 0; g < NVG; g++) {
            float4 h4 = hs4[g];
            float4 w0 = wv[g * 4 + 0], w1 = wv[g * 4 + 1],
                   w2 = wv[g * 4 + 2], w3 = wv[g * 4 + 3];
            a0 = fmaf(w0.x, h4.x, a0); a0 = fmaf(w0.y, h4.y, a0);
            a0 = fmaf(w0.z, h4.z, a0); a0 = fmaf(w0.w, h4.w, a0);
            a1 = fmaf(w1.x, h4.x, a1); a1 = fmaf(w1.y, h4.y, a1);
            a1 = fmaf(w1.z, h4.z, a1); a1 = fmaf(w1.w, h4.w, a1);
            a2 = fmaf(w2.x, h4.x, a2); a2 = fmaf(w2.y, h4.y, a2);
            a2 = fmaf(w2.z, h4.z, a2); a2 = fmaf(w2.w, h4.w, a2);
            a3 = fmaf(w3.x, h4.x, a3); a3 = fmaf(w3.y, h4.y, a3);
            a3 = fmaf(w3.z, h4.z, a3); a3 = fmaf(w3.w, h4.w, a3);
        }
        /* AGPR phase */
        #pragma unroll
        for (int g = 0; g < NAG; g++) {
            float4 h4 = hs4[NVG + g];
            #pragma unroll
            for (int q = 0; q < 4; q++) {
                int base = (g * 4 + q) * 4;
                float w0, w1, w2, w3;
                asm volatile("v_accvgpr_read_b32 %0, %1" : "=v"(w0) : "a"(ag[base + 0]));
                asm volatile("v_accvgpr_read_b32 %0, %1" : "=v"(w1) : "a"(ag[base + 1]));
                asm volatile("v_accvgpr_read_b32 %0, %1" : "=v"(w2) : "a"(ag[base + 2]));
                asm volatile("v_accvgpr_read_b32 %0, %1" : "=v"(w3) : "a"(ag[base + 3]));
                float acc = (q == 0) ? a0 : (q == 1) ? a1 : (q == 2) ? a2 : a3;
                acc = fmaf(w0, h4.x, acc); acc = fmaf(w1, h4.y, acc);
                acc = fmaf(w2, h4.z, acc); acc = fmaf(w3, h4.w, acc);
                if (q == 0) a0 = acc; else if (q == 1) a1 = acc;
                else if (q == 2) a2 = acc; else a3 = acc;
            }
        }
        /* LDS phase */
        #pragma unroll
        for (int g = 0; g < NLD; g++) {
            float4 h4 = hs4[NVG + NAG + g];
            float4 w0 = sW[((g * 4 + 0) << 8) + t], w1 = sW[((g * 4 + 1) << 8) + t];
            float4 w2 = sW[((g * 4 + 2) << 8) + t], w3 = sW[((g * 4 + 3) << 8) + t];
            a0 = fmaf(w0.x, h4.x, a0); a0 = fmaf(w0.y, h4.y, a0);
            a0 = fmaf(w0.z, h4.z, a0); a0 = fmaf(w0.w, h4.w, a0);
            a1 = fmaf(w1.x, h4.x, a1); a1 = fmaf(w1.y, h4.y, a1);
            a1 = fmaf(w1.z, h4.z, a1); a1 = fmaf(w1.w, h4.w, a1);
            a2 = fmaf(w2.x, h4.x, a2); a2 = fmaf(w2.y, h4.y, a2);
            a2 = fmaf(w2.z, h4.z, a2); a2 = fmaf(w2.w, h4.w, a2);
            a3 = fmaf(w3.x, h4.x, a3); a3 = fmaf(w3.y, h4.y, a3);
            a3 = fmaf(w3.z, h4.z, a3); a3 = fmaf(w3.w, h4.w, a3);
        }
        /* streamed phase */
        #pragma unroll 4
        for (int gs = 0; gs < NST; gs++) {
            float4 w0 = ws0[gs << 8];
            float4 w1 = ws1[gs << 8];
            float4 w2 = ws2[gs << 8];
            float4 w3 = ws3[gs << 8];
            float4 h4 = hs4[GST + gs];
            a0 = fmaf(w0.x, h4.x, a0); a0 = fmaf(w0.y, h4.y, a0);
            a0 = fmaf(w0.z, h4.z, a0); a0 = fmaf(w0.w, h4.w, a0);
            a1 = fmaf(w1.x, h4.x, a1); a1 = fmaf(w1.y, h4.y, a1);
            a1 = fmaf(w1.z, h4.z, a1); a1 = fmaf(w1.w, h4.w, a1);
            a2 = fmaf(w2.x, h4.x, a2); a2 = fmaf(w2.y, h4.y, a2);
            a2 = fmaf(w2.z, h4.z, a2); a2 = fmaf(w2.w, h4.w, a2);
            a3 = fmaf(w3.x, h4.x, a3); a3 = fmaf(w3.y, h4.y, a3);
            a3 = fmaf(w3.z, h4.z, a3); a3 = fmaf(w3.w, h4.w, a3);
        }

        /* activation (thread-local; no hs dependency) */
        float ig = sigf(a0), fg = sigf(a1), tg = tanhf(a2), og = sigf(a3);
        cst = fg * cst + ig * tg;
        float hn = og * tanhf(cst);

        __syncthreads();   /* B1: all hs reads of this step done */
        hs[t] = hn;

        int l = t & 63, wv2 = t >> 6;
        #pragma unroll
        for (int tt = 0; tt < T; tt++) {
            float v = hn * mw[tt];
            v += __shfl_xor(v, 32, 64); v += __shfl_xor(v, 16, 64);
            v += __shfl_xor(v, 8, 64);  v += __shfl_xor(v, 4, 64);
            v += __shfl_xor(v, 2, 64);  v += __shfl_xor(v, 1, 64);
            if (l == 0) red[tt][wv2] = v;
        }
        __syncthreads();   /* B2: hs updated + red ready */
        if (t < T)
            emdst[((size_t)b * S + sp) * T + t] = red[t][0] + red[t][1] + red[t][2] + red[t][3];
    }
}

/* Viterbi forward: one wave per batch, lane t = tag. Strict-> ascending scan
   matches jnp.argmax first-index tie-breaking. */
__global__ __launch_bounds__(64) void k_vit(const int* __restrict__ data,
                                            const float* __restrict__ strans,
                                            const float* __restrict__ trans,
                                            const float* __restrict__ etrans,
                                            const float* __restrict__ mlpb,
                                            float* __restrict__ out,
                                            char* __restrict__ ws) {
    int b = blockIdx.x, t = threadIdx.x;
    const float* emf = (const float*)(ws + OFF_EMF);
    const float* emb = (const float*)(ws + OFF_EMB);
    char* bp = ws + OFF_BP;
    int*  lt = (int*)(ws + OFF_LT);
    bool act = t < T;

    float trp[T];
    float mb = 0.0f;
    if (act) {
        #pragma unroll
        for (int p = 0; p < T; p++) trp[p] = trans[p * T + t];
        mb = mlpb[t];
    }
    float score = -1e30f;
    if (act) score = strans[t] + emf[(b * S) * T + t] + emb[(b * S) * T + t] + mb;

    for (int s = 1; s < S; s++) {
        float e = 0.0f;
        if (act) e = emf[(b * S + s) * T + t] + emb[(b * S + s) * T + t] + mb;
        float best = __shfl(score, 0, 64) + trp[0];
        int bpi = 0;
        #pragma unroll
        for (int p = 1; p < T; p++) {
            float cand = __shfl(score, p, 64) + trp[p];
            if (cand > best) { best = cand; bpi = p; }
        }
        int m = data[b * S + s] != 0;
        if (act) {
            score = m ? (best + e) : score;
            bp[((size_t)(s - 1) * B + b) * 16 + t] = (char)bpi;
        }
    }
    float fin = act ? score + etrans[t] : -1e30f;
    float bv = __shfl(fin, 0, 64);
    int bi = 0;
    #pragma unroll
    for (int p = 1; p < T; p++) {
        float v = __shfl(fin, p, 64);
        if (v > bv) { bv = v; bi = p; }
    }
    if (t == 0) { out[B * S + b] = bv; lt[b] = bi; }
}

/* Backtrack: thread = batch; bp row address is tag-independent -> pipelined loads */
__global__ __launch_bounds__(128) void k_back(const int* __restrict__ data, char* __restrict__ ws) {
    int b = threadIdx.x;
    const int4* bp4 = (const int4*)(ws + OFF_BP);
    const int*  lt  = (const int*)(ws + OFF_LT);
    int* pt = (int*)(ws + OFF_PT);
    int tag = lt[b];
    pt[(S - 1) * B + b] = tag;
    for (int p = S - 2; p >= 0; p--) {
        int4 r = bp4[(size_t)p * B + b];
        int m = data[b * S + p + 1] != 0;
        unsigned w = (unsigned)(tag < 8 ? (tag < 4 ? r.x : r.y) : r.z);
        int nt = (int)((w >> ((tag & 3) * 8)) & 0xff);
        tag = m ? nt : tag;
        pt[p * B + b] = tag;
    }
}

/* paths -> float output with mask zeroing */
__global__ __launch_bounds__(256) void k_fin(const int* __restrict__ data,
                                             float* __restrict__ out,
                                             const char* __restrict__ ws) {
    int tid = blockIdx.x * 256 + threadIdx.x;   /* 65536 */
    const int* pt = (const int*)(ws + OFF_PT);
    int b = tid >> 9, p = tid & 511;
    out[tid] = (data[tid] != 0) ? (float)pt[p * B + b] : 0.0f;
}

extern "C" void kernel_launch(void* const* d_in, const int* in_sizes, int n_in,
                              void* d_out, int out_size, void* d_ws, size_t ws_size,
                              hipStream_t stream) {
    const int*   data = (const int*)d_in[0];
    /* d_in[1] = mask (bool) — unused; mask == (data != 0) */
    const float* emb  = (const float*)d_in[2];
    const float* wihf = (const float*)d_in[3];
    const float* whhf = (const float*)d_in[4];
    const float* bf   = (const float*)d_in[5];
    const float* wihb = (const float*)d_in[6];
    const float* whhb = (const float*)d_in[7];
    const float* bb   = (const float*)d_in[8];
    const float* mlpW = (const float*)d_in[9];
    const float* mlpb = (const float*)d_in[10];
    const float* st   = (const float*)d_in[11];
    const float* tr   = (const float*)d_in[12];
    const float* et   = (const float*)d_in[13];
    float* out = (float*)d_out;
    char*  ws  = (char*)d_ws;

    hipLaunchKernelGGL(k_pemb, dim3(750),  dim3(256), 0, stream, emb, wihf, bf, wihb, bb, ws);
    hipLaunchKernelGGL(k_prep, dim3(288),  dim3(256), 0, stream, whhf, whhb, ws);
    hipLaunchKernelGGL(k_lstm, dim3(256),  dim3(256), 0, stream, data, whhf, whhb, mlpW, ws);
    hipLaunchKernelGGL(k_vit,  dim3(128),  dim3(64),  0, stream, data, st, tr, et, mlpb, out, ws);
    hipLaunchKernelGGL(k_back, dim3(1),    dim3(128), 0, stream, data, ws);
    hipLaunchKernelGGL(k_fin,  dim3(256),  dim3(256), 0, stream, data, out, ws);
}

// Round 11
// 5121.220 us; speedup vs baseline: 1.4561x; 1.4561x over previous
//
#include <hip/hip_runtime.h>
#include <math.h>
#include <stdint.h>

#define B 128
#define S 512
#define V 6000
#define E 100
#define H 256
#define G4 1024   /* 4*H */
#define T 9

/* per-row float4 k-group split (64 groups of 4 cols per gate row) */
#define NAGR 16            /* k-groups [0,16)  in AGPRs: 2 rows x 16 x 4 = 128 "a" regs */
#define NLDR 9             /* k-groups [16,25) in dynamic LDS: 9*1024*16 = 147,456 B */
#define NSTR 39            /* k-groups [25,64) streamed: 624 KB/step/dir */
#define GSTR (NAGR + NLDR) /* 25 */

/* dynamic-LDS layout (bytes) */
#define SM_W    0u                       /* float4 sW[9*1024]      147,456 */
#define SM_HS   147456u                  /* float hs[256]            1,024 */
#define SM_GB   148480u                  /* float gbuf[1024]         4,096 */
#define SM_RED  152576u                  /* float red[T][4]            144 */
#define SM_TOK  152720u                  /* int toks[512]            2,048 */
#define SM_SIZE 154768u

/* workspace byte offsets (256-aligned) */
#define OFF_PEMB_F 0u
#define PEMB_BYTES (V*G4*4u)                    /* 24,576,000 */
#define OFF_PEMB_B (OFF_PEMB_F + PEMB_BYTES)
#define OFF_EMF    (OFF_PEMB_B + PEMB_BYTES)    /* 49,152,000 */
#define EM_BYTES   (B*S*T*4u)                   /* 2,359,296 */
#define OFF_EMB    (OFF_EMF + EM_BYTES)
#define OFF_BP     (OFF_EMB + EM_BYTES)         /* 53,870,592 */
#define BP_BYTES   ((S-1)*B*16u)                /* 1,046,528 */
#define OFF_LT     (OFF_BP + BP_BYTES)
#define OFF_PT     (OFF_LT + 512u)
/* Streamed-W: 2 dirs x 39 groups x 1024 rows x 16 B = 1,277,952 B.
   OVERLAYS BP/LT/PT (1,309,184 B): k_prep writes + k_lstm reads strictly
   BEFORE k_vit/k_back write BP/LT/PT (stream-ordered). */
#define OFF_WSTREAM OFF_BP

__device__ __forceinline__ float sigf(float x) { return 1.0f / (1.0f + expf(-x)); }

/* pemb[v][g4] = bias[g4] + sum_e emb[v][e] * W_ih[g4][e],  g4 = q*H + j */
__global__ __launch_bounds__(256) void k_pemb(const float* __restrict__ emb,
                                              const float* __restrict__ wf, const float* __restrict__ bf,
                                              const float* __restrict__ wb, const float* __restrict__ bb,
                                              char* __restrict__ ws) {
    int blk = blockIdx.x;                   /* 0..749 */
    int d   = blk >= 375;
    int vb  = d ? blk - 375 : blk;
    const float* W    = d ? wb : wf;
    const float* bias = d ? bb : bf;
    float* pe = (float*)(ws + (d ? OFF_PEMB_B : OFF_PEMB_F));

    __shared__ float es[16 * E];
    for (int i = threadIdx.x; i < 16 * E; i += 256) es[i] = emb[vb * 16 * E + i];
    __syncthreads();

    int j = threadIdx.x;
    float acc[4][16];
    #pragma unroll
    for (int q = 0; q < 4; q++) {
        float bq = bias[q * H + j];
        #pragma unroll
        for (int v = 0; v < 16; v++) acc[q][v] = bq;
    }
    for (int e = 0; e < E; e++) {
        float w0 = W[(0 * H + j) * E + e];
        float w1 = W[(1 * H + j) * E + e];
        float w2 = W[(2 * H + j) * E + e];
        float w3 = W[(3 * H + j) * E + e];
        #pragma unroll
        for (int v = 0; v < 16; v++) {
            float x = es[v * E + e];
            acc[0][v] += w0 * x; acc[1][v] += w1 * x;
            acc[2][v] += w2 * x; acc[3][v] += w3 * x;
        }
    }
    for (int v = 0; v < 16; v++)
        #pragma unroll
        for (int q = 0; q < 4; q++)
            pe[(vb * 16 + v) * G4 + q * H + j] = acc[q][v];
}

/* streamed-W layout: wstr[(d*NSTR + gi)*1024 + r] = float4 W_d[r][4*(GSTR+gi)..+3]
   -> per step, lane r loads consecutive float4 (coalesced 16 B/lane) */
__global__ __launch_bounds__(256) void k_prep(const float* __restrict__ whhf,
                                              const float* __restrict__ whhb,
                                              char* __restrict__ ws) {
    int tid = blockIdx.x * 256 + threadIdx.x;   /* 2*39*1024 = 79872 */
    if (tid >= 2 * NSTR * 1024) return;
    int d   = tid >= NSTR * 1024;
    int idx = d ? tid - NSTR * 1024 : tid;
    int gi = idx >> 10, r = idx & 1023;
    const float* whh = d ? whhb : whhf;
    float4* wstr = (float4*)(ws + OFF_WSTREAM);
    const float4* src = (const float4*)(whh + (size_t)r * H);
    wstr[((size_t)(d * NSTR + gi) << 10) + r] = src[GSTR + gi];
}

/* Single-CU LSTM: 256 blocks (dir d = blk>>7, batch b = blk&127) x 512 thr
   (8 waves, 2/SIMD -- R9's proven latency-hiding config). Thread t owns gate
   rows t and t+512. Per row: k-groups [0,16) in AGPRs (128 "a"-constrained
   floats/thread; R10 proved the mechanism -- the allocator cannot spill or
   rematerialize them, and the AGPR demand itself caps occupancy at 2
   waves/SIMD so the 256-unified budget is structural), [16,25) in dynamic
   LDS (147 KB of the 160 KB/CU file -- past the 64 KB static cap), [25,64)
   streamed from L2 (624 KB/step, k-major, shared by all same-dir blocks).
   No cross-CU communication. 2 barriers/step. */
__global__ __launch_bounds__(512, 2) void k_lstm(const int* __restrict__ data,
                                                 const float* __restrict__ whhf,
                                                 const float* __restrict__ whhb,
                                                 const float* __restrict__ mlpW,
                                                 char* __restrict__ ws) {
    extern __shared__ char smem[];
    float4* sW  = (float4*)(smem + SM_W);      /* [g<<10 | r] */
    float*  hs  = (float*)(smem + SM_HS);
    float*  gbuf= (float*)(smem + SM_GB);
    float (*red)[4] = (float(*)[4])(smem + SM_RED);
    int*    toks= (int*)(smem + SM_TOK);

    int blk = blockIdx.x;
    int d = blk >> 7, b = blk & 127;
    const float* whh = d ? whhb : whhf;
    const float* pe  = (const float*)(ws + (d ? OFF_PEMB_B : OFF_PEMB_F));
    float* emdst = (float*)(ws + (d ? OFF_EMB : OFF_EMF));
    const float4* wstrD = (const float4*)(ws + OFF_WSTREAM) + ((size_t)(d * NSTR) << 10);

    int t = threadIdx.x;                       /* 0..511 */
    int r0 = t, r1 = t + 512;
    const float4* wrow0 = (const float4*)(whh + (size_t)r0 * H);
    const float4* wrow1 = (const float4*)(whh + (size_t)r1 * H);

    /* --- AGPR W: k-groups [0,16) for both rows = 128 AGPR floats --- */
    float agA[NAGR * 4], agB[NAGR * 4];
    #pragma unroll
    for (int g = 0; g < NAGR; g++) {
        float4 wa = wrow0[g];
        float4 wb2 = wrow1[g];
        asm volatile("v_accvgpr_write_b32 %0, %1" : "=a"(agA[g * 4 + 0]) : "v"(wa.x));
        asm volatile("v_accvgpr_write_b32 %0, %1" : "=a"(agA[g * 4 + 1]) : "v"(wa.y));
        asm volatile("v_accvgpr_write_b32 %0, %1" : "=a"(agA[g * 4 + 2]) : "v"(wa.z));
        asm volatile("v_accvgpr_write_b32 %0, %1" : "=a"(agA[g * 4 + 3]) : "v"(wa.w));
        asm volatile("v_accvgpr_write_b32 %0, %1" : "=a"(agB[g * 4 + 0]) : "v"(wb2.x));
        asm volatile("v_accvgpr_write_b32 %0, %1" : "=a"(agB[g * 4 + 1]) : "v"(wb2.y));
        asm volatile("v_accvgpr_write_b32 %0, %1" : "=a"(agB[g * 4 + 2]) : "v"(wb2.z));
        asm volatile("v_accvgpr_write_b32 %0, %1" : "=a"(agB[g * 4 + 3]) : "v"(wb2.w));
    }
    /* --- LDS W: k-groups [16,25) --- */
    #pragma unroll
    for (int g = 0; g < NLDR; g++) {
        sW[(g << 10) + r0] = wrow0[NAGR + g];
        sW[(g << 10) + r1] = wrow1[NAGR + g];
    }

    toks[t] = data[b * S + t];                 /* S == 512 == blockDim */

    float mw[T];
    if (t < 256) {
        #pragma unroll
        for (int tt = 0; tt < T; tt++) mw[tt] = mlpW[tt * (2 * H) + d * H + t];
    }
    if (t < H) hs[t] = 0.0f;
    float cst = 0.0f;
    __syncthreads();

    const float4* hs4 = (const float4*)hs;
    const float4* wsp0 = wstrD + r0;
    const float4* wsp1 = wstrD + r1;

    float pf0, pf1;
    {
        int sp0 = d ? (S - 1) : 0;
        size_t tok = (size_t)toks[sp0];
        pf0 = pe[(tok << 10) + r0];
        pf1 = pe[(tok << 10) + r1];
    }

    for (int ss = 0; ss < S; ss++) {
        int sp = d ? (S - 1 - ss) : ss;
        float acc0 = pf0, acc1 = pf1;
        if (ss + 1 < S) {
            int spn = d ? (S - 2 - ss) : (ss + 1);
            size_t tok = (size_t)toks[spn];
            pf0 = pe[(tok << 10) + r0];
            pf1 = pe[(tok << 10) + r1];
        }

        /* AGPR phase: k-groups [0,16) */
        #pragma unroll
        for (int g = 0; g < NAGR; g++) {
            float4 h4 = hs4[g];
            float a0, a1, a2, a3, b0v, b1v, b2v, b3v;
            asm volatile("v_accvgpr_read_b32 %0, %1" : "=v"(a0)  : "a"(agA[g * 4 + 0]));
            asm volatile("v_accvgpr_read_b32 %0, %1" : "=v"(a1)  : "a"(agA[g * 4 + 1]));
            asm volatile("v_accvgpr_read_b32 %0, %1" : "=v"(a2)  : "a"(agA[g * 4 + 2]));
            asm volatile("v_accvgpr_read_b32 %0, %1" : "=v"(a3)  : "a"(agA[g * 4 + 3]));
            asm volatile("v_accvgpr_read_b32 %0, %1" : "=v"(b0v) : "a"(agB[g * 4 + 0]));
            asm volatile("v_accvgpr_read_b32 %0, %1" : "=v"(b1v) : "a"(agB[g * 4 + 1]));
            asm volatile("v_accvgpr_read_b32 %0, %1" : "=v"(b2v) : "a"(agB[g * 4 + 2]));
            asm volatile("v_accvgpr_read_b32 %0, %1" : "=v"(b3v) : "a"(agB[g * 4 + 3]));
            acc0 = fmaf(a0, h4.x, acc0);  acc1 = fmaf(b0v, h4.x, acc1);
            acc0 = fmaf(a1, h4.y, acc0);  acc1 = fmaf(b1v, h4.y, acc1);
            acc0 = fmaf(a2, h4.z, acc0);  acc1 = fmaf(b2v, h4.z, acc1);
            acc0 = fmaf(a3, h4.w, acc0);  acc1 = fmaf(b3v, h4.w, acc1);
        }
        /* LDS phase: k-groups [16,25) */
        #pragma unroll
        for (int g = 0; g < NLDR; g++) {
            float4 w0 = sW[(g << 10) + r0];
            float4 w1 = sW[(g << 10) + r1];
            float4 h4 = hs4[NAGR + g];
            acc0 = fmaf(w0.x, h4.x, acc0);  acc1 = fmaf(w1.x, h4.x, acc1);
            acc0 = fmaf(w0.y, h4.y, acc0);  acc1 = fmaf(w1.y, h4.y, acc1);
            acc0 = fmaf(w0.z, h4.z, acc0);  acc1 = fmaf(w1.z, h4.z, acc1);
            acc0 = fmaf(w0.w, h4.w, acc0);  acc1 = fmaf(w1.w, h4.w, acc1);
        }
        /* streamed phase: k-groups [25,64) */
        #pragma unroll 4
        for (int g = 0; g < NSTR; g++) {
            float4 w0 = wsp0[(size_t)g << 10];
            float4 w1 = wsp1[(size_t)g << 10];
            float4 h4 = hs4[GSTR + g];
            acc0 = fmaf(w0.x, h4.x, acc0);  acc1 = fmaf(w1.x, h4.x, acc1);
            acc0 = fmaf(w0.y, h4.y, acc0);  acc1 = fmaf(w1.y, h4.y, acc1);
            acc0 = fmaf(w0.z, h4.z, acc0);  acc1 = fmaf(w1.z, h4.z, acc1);
            acc0 = fmaf(w0.w, h4.w, acc0);  acc1 = fmaf(w1.w, h4.w, acc1);
        }
        gbuf[r0] = acc0;
        gbuf[r1] = acc1;
        __syncthreads();   /* B1: gates complete, hs reads done */

        if (t < 256) {
            float gi = gbuf[t], gf = gbuf[H + t], gg = gbuf[2 * H + t], go = gbuf[3 * H + t];
            float ig = sigf(gi), fg = sigf(gf), tg = tanhf(gg), og = sigf(go);
            cst = fg * cst + ig * tg;
            float hn = og * tanhf(cst);
            hs[t] = hn;
            int l = t & 63, wv = t >> 6;
            #pragma unroll
            for (int tt = 0; tt < T; tt++) {
                float v = hn * mw[tt];
                v += __shfl_xor(v, 32, 64); v += __shfl_xor(v, 16, 64);
                v += __shfl_xor(v, 8, 64);  v += __shfl_xor(v, 4, 64);
                v += __shfl_xor(v, 2, 64);  v += __shfl_xor(v, 1, 64);
                if (l == 0) red[tt][wv] = v;
            }
        }
        __syncthreads();   /* B2: hs updated + red ready */
        if (t < T)
            emdst[((size_t)b * S + sp) * T + t] = red[t][0] + red[t][1] + red[t][2] + red[t][3];
    }
}

/* Viterbi forward: one wave per batch, lane t = tag. Strict-> ascending scan
   matches jnp.argmax first-index tie-breaking. */
__global__ __launch_bounds__(64) void k_vit(const int* __restrict__ data,
                                            const float* __restrict__ strans,
                                            const float* __restrict__ trans,
                                            const float* __restrict__ etrans,
                                            const float* __restrict__ mlpb,
                                            float* __restrict__ out,
                                            char* __restrict__ ws) {
    int b = blockIdx.x, t = threadIdx.x;
    const float* emf = (const float*)(ws + OFF_EMF);
    const float* emb = (const float*)(ws + OFF_EMB);
    char* bp = ws + OFF_BP;
    int*  lt = (int*)(ws + OFF_LT);
    bool act = t < T;

    float trp[T];
    float mb = 0.0f;
    if (act) {
        #pragma unroll
        for (int p = 0; p < T; p++) trp[p] = trans[p * T + t];
        mb = mlpb[t];
    }
    float score = -1e30f;
    if (act) score = strans[t] + emf[(b * S) * T + t] + emb[(b * S) * T + t] + mb;

    for (int s = 1; s < S; s++) {
        float e = 0.0f;
        if (act) e = emf[(b * S + s) * T + t] + emb[(b * S + s) * T + t] + mb;
        float best = __shfl(score, 0, 64) + trp[0];
        int bpi = 0;
        #pragma unroll
        for (int p = 1; p < T; p++) {
            float cand = __shfl(score, p, 64) + trp[p];
            if (cand > best) { best = cand; bpi = p; }
        }
        int m = data[b * S + s] != 0;
        if (act) {
            score = m ? (best + e) : score;
            bp[((size_t)(s - 1) * B + b) * 16 + t] = (char)bpi;
        }
    }
    float fin = act ? score + etrans[t] : -1e30f;
    float bv = __shfl(fin, 0, 64);
    int bi = 0;
    #pragma unroll
    for (int p = 1; p < T; p++) {
        float v = __shfl(fin, p, 64);
        if (v > bv) { bv = v; bi = p; }
    }
    if (t == 0) { out[B * S + b] = bv; lt[b] = bi; }
}

/* Backtrack: thread = batch; bp row address is tag-independent -> pipelined loads */
__global__ __launch_bounds__(128) void k_back(const int* __restrict__ data, char* __restrict__ ws) {
    int b = threadIdx.x;
    const int4* bp4 = (const int4*)(ws + OFF_BP);
    const int*  lt  = (const int*)(ws + OFF_LT);
    int* pt = (int*)(ws + OFF_PT);
    int tag = lt[b];
    pt[(S - 1) * B + b] = tag;
    for (int p = S - 2; p >= 0; p--) {
        int4 r = bp4[(size_t)p * B + b];
        int m = data[b * S + p + 1] != 0;
        unsigned w = (unsigned)(tag < 8 ? (tag < 4 ? r.x : r.y) : r.z);
        int nt = (int)((w >> ((tag & 3) * 8)) & 0xff);
        tag = m ? nt : tag;
        pt[p * B + b] = tag;
    }
}

/* paths -> float output with mask zeroing */
__global__ __launch_bounds__(256) void k_fin(const int* __restrict__ data,
                                             float* __restrict__ out,
                                             const char* __restrict__ ws) {
    int tid = blockIdx.x * 256 + threadIdx.x;   /* 65536 */
    const int* pt = (const int*)(ws + OFF_PT);
    int b = tid >> 9, p = tid & 511;
    out[tid] = (data[tid] != 0) ? (float)pt[p * B + b] : 0.0f;
}

extern "C" void kernel_launch(void* const* d_in, const int* in_sizes, int n_in,
                              void* d_out, int out_size, void* d_ws, size_t ws_size,
                              hipStream_t stream) {
    const int*   data = (const int*)d_in[0];
    /* d_in[1] = mask (bool) — unused; mask == (data != 0) */
    const float* emb  = (const float*)d_in[2];
    const float* wihf = (const float*)d_in[3];
    const float* whhf = (const float*)d_in[4];
    const float* bf   = (const float*)d_in[5];
    const float* wihb = (const float*)d_in[6];
    const float* whhb = (const float*)d_in[7];
    const float* bb   = (const float*)d_in[8];
    const float* mlpW = (const float*)d_in[9];
    const float* mlpb = (const float*)d_in[10];
    const float* st   = (const float*)d_in[11];
    const float* tr   = (const float*)d_in[12];
    const float* et   = (const float*)d_in[13];
    float* out = (float*)d_out;
    char*  ws  = (char*)d_ws;

    /* raise the dynamic-LDS cap past 64 KB (attribute set, not a stream op;
       idempotent -> graph-capture safe) */
    static int lds_attr_done = 0;
    (void)lds_attr_done;
    hipFuncSetAttribute(reinterpret_cast<const void*>(k_lstm),
                        hipFuncAttributeMaxDynamicSharedMemorySize, 160 * 1024);

    hipLaunchKernelGGL(k_pemb, dim3(750),  dim3(256), 0, stream, emb, wihf, bf, wihb, bb, ws);
    hipLaunchKernelGGL(k_prep, dim3(312),  dim3(256), 0, stream, whhf, whhb, ws);
    hipLaunchKernelGGL(k_lstm, dim3(256),  dim3(512), SM_SIZE, stream, data, whhf, whhb, mlpW, ws);
    hipLaunchKernelGGL(k_vit,  dim3(128),  dim3(64),  0, stream, data, st, tr, et, mlpb, out, ws);
    hipLaunchKernelGGL(k_back, dim3(1),    dim3(128), 0, stream, data, ws);
    hipLaunchKernelGGL(k_fin,  dim3(256),  dim3(256), 0, stream, data, out, ws);
}